// Round 9
// baseline (191.923 us; speedup 1.0000x reference)
//
#include <hip/hip_runtime.h>
#include <math.h>

// StatefulRosenberg R16: R15 + two chunks per emit block (pipelined).
//
// R15 = 174.1 us (best). Emit ~35 us at 3.8 TB/s HBM vs ~21 us floor.
// R16 theory: a block owning chunks (2c, 2c+1) gets chunk 2c+1's prefix
// FREE (= chunk 2c prefix + chunk 2c total, computed in-block anyway).
// So per 4096 elements: ONE butterfly + ONE set of predicated partial
// loads + ONE barrier (R15 needed 2 of each). The two wave scans (a,b)
// are independent f64 shfl chains -> compiler interleaves them through
// the ds_bpermute pipe (~2x ILP on the serial core). Loads issued in
// consumption order (f0a -> partials -> oqa -> f0b -> oqb): monotone
// vmcnt drain, each consumer waits only for its own data.
//
// Dead-lane ledger (measured): grid.sync/spin ~0.13us/block (R8,R12);
// per-wave barrier-free prefix (R13/R14: replicates butterfly 4x);
// VPT=16 flat (R14: f0 LLC residency lost, FETCH +25MB); nt wav stores
// (R9: +30MB write amp). Kept: oq pre-scan hoist (R9), regular wav
// stores, nt oq loads, f64 scan infra + one f64 wrap + f32 element accum.
// Spill watch: VGPR cap 64 under (256,8); signature = FETCH/WRITE
// inflating off 66.5/65.5 MB.

constexpr int BATCH   = 16;
constexpr int T       = 1048576;
constexpr int THREADS = 256;
constexpr int VPT     = 8;                // elements per thread per chunk
constexpr int CHUNK   = THREADS * VPT;    // 2048
constexpr int NCHUNK  = T / CHUNK;        // 512
constexpr int NBX     = NCHUNK / 2;       // 256 emit blocks per row

#define INV_SR (1.0f / 48000.0f)

typedef float v4f __attribute__((ext_vector_type(4)));

__device__ __forceinline__ double tree8d(const float* s) {
    return (((double)s[0] + (double)s[1]) + ((double)s[2] + (double)s[3]))
         + (((double)s[4] + (double)s[5]) + ((double)s[6] + (double)s[7]));
}

// ---------------- Pass 1: per-chunk fp64 sums (unchanged) ----------------
__global__ __launch_bounds__(THREADS, 8) void k_chunk_sums(
    const float* __restrict__ f0, double* __restrict__ partial)
{
    const int chunk = blockIdx.x;
    const int row   = blockIdx.y;
    const v4f* base = (const v4f*)(f0 + (size_t)row * T
                     + (size_t)chunk * CHUNK + (size_t)threadIdx.x * VPT);
    v4f v0 = base[0], v1 = base[1];       // regular loads: warm LLC for pass 2
    float st[VPT];
    st[0]=v0.x*INV_SR; st[1]=v0.y*INV_SR; st[2]=v0.z*INV_SR; st[3]=v0.w*INV_SR;
    st[4]=v1.x*INV_SR; st[5]=v1.y*INV_SR; st[6]=v1.z*INV_SR; st[7]=v1.w*INV_SR;
    double s = tree8d(st);
#pragma unroll
    for (int off = 32; off > 0; off >>= 1)
        s += __shfl_down(s, off, 64);
    __shared__ double ws[THREADS / 64];
    const int lane = threadIdx.x & 63, wid = threadIdx.x >> 6;
    if (lane == 0) ws[wid] = s;
    __syncthreads();
    if (threadIdx.x == 0)
        partial[row * NCHUNK + chunk] = ws[0] + ws[1] + ws[2] + ws[3];
}

// ---------------- Pass 2: two chunks per block, one barrier --------------
__global__ __launch_bounds__(THREADS, 8) void k_emit(
    const float* __restrict__ f0, const float* __restrict__ oq,
    const double* __restrict__ partial, const float* __restrict__ phase_state,
    float* __restrict__ wav, float* __restrict__ next_state)
{
    const int bx   = blockIdx.x;          // 0..255
    const int row  = blockIdx.y;
    const int c0   = 2 * bx;              // first owned chunk
    const int lane = threadIdx.x & 63, wid = threadIdx.x >> 6;
    const size_t base_a = (size_t)row * T + (size_t)c0 * CHUNK
                        + (size_t)threadIdx.x * VPT;
    const size_t base_b = base_a + CHUNK;

    __shared__ double rs[THREADS / 64];   // chunk-prefix partial reduce
    __shared__ double wsA[THREADS / 64];  // chunk-a wave inclusive totals
    __shared__ double wsB[THREADS / 64];  // chunk-b wave inclusive totals

    // ---- loads in CONSUMPTION order (monotone vmcnt drain) ----
    // (1) f0a: first consumer (tsum_a); LLC-hot
    const v4f* fa = (const v4f*)(f0 + base_a);
    v4f fa0 = fa[0], fa1 = fa[1];
    // (2) partials: butterfly; L2-hot. prefix covers chunks [0, c0)
    double pv = 0.0;
    if ((int)threadIdx.x < c0)       pv  = partial[row * NCHUNK + threadIdx.x];
    if ((int)threadIdx.x + 256 < c0) pv += partial[row * NCHUNK + threadIdx.x + 256];
    const float pstate = phase_state[row];
    // (3) oqa: consumed by emit-a
    const v4f* oa = (const v4f*)(oq + base_a);
    v4f oa0 = __builtin_nontemporal_load(oa + 0);
    v4f oa1 = __builtin_nontemporal_load(oa + 1);
    // (4) f0b: consumed by tsum_b
    const v4f* fbp = (const v4f*)(f0 + base_b);
    v4f fb0 = fbp[0], fb1 = fbp[1];
    // (5) oqb: consumed last by emit-b
    const v4f* ob = (const v4f*)(oq + base_b);
    v4f ob0 = __builtin_nontemporal_load(ob + 0);
    v4f ob1 = __builtin_nontemporal_load(ob + 1);

    // ---- f32 steps + per-thread fp64 sums for both chunks ----
    float sa[VPT], sb[VPT];
    sa[0]=fa0.x*INV_SR; sa[1]=fa0.y*INV_SR; sa[2]=fa0.z*INV_SR; sa[3]=fa0.w*INV_SR;
    sa[4]=fa1.x*INV_SR; sa[5]=fa1.y*INV_SR; sa[6]=fa1.z*INV_SR; sa[7]=fa1.w*INV_SR;
    sb[0]=fb0.x*INV_SR; sb[1]=fb0.y*INV_SR; sb[2]=fb0.z*INV_SR; sb[3]=fb0.w*INV_SR;
    sb[4]=fb1.x*INV_SR; sb[5]=fb1.y*INV_SR; sb[6]=fb1.z*INV_SR; sb[7]=fb1.w*INV_SR;
    double tsA = tree8d(sa);
    double tsB = tree8d(sb);

    // ---- chunk prefix butterfly (one per 4096 elements now) ----
#pragma unroll
    for (int off = 32; off > 0; off >>= 1)
        pv += __shfl_down(pv, off, 64);
    if (lane == 0) rs[wid] = pv;

    // ---- two independent wave scans: interleaved f64 shfl chains ----
    double incA = tsA, incB = tsB;
#pragma unroll
    for (int off = 1; off < 64; off <<= 1) {
        double nA = __shfl_up(incA, off, 64);
        double nB = __shfl_up(incB, off, 64);
        if (lane >= off) { incA += nA; incB += nB; }
    }
    if (lane == 63) { wsA[wid] = incA; wsB[wid] = incB; }
    __syncthreads();                       // the ONLY barrier

    const double chunkpref = rs[0] + rs[1] + rs[2] + rs[3];
    const double totalA    = wsA[0] + wsA[1] + wsA[2] + wsA[3];

    double runA = (double)pstate + chunkpref + (incA - tsA);
    double runB = (double)pstate + chunkpref + totalA + (incB - tsB);
#pragma unroll
    for (int w = 0; w < THREADS / 64; ++w) {
        if (w < wid) { runA += wsA[w]; runB += wsB[w]; }
    }

    // next_state: unwrapped final phase (last block, thread 0)
    if (bx == NBX - 1 && threadIdx.x == 0)
        next_state[row] = (float)((double)pstate + chunkpref + totalA
                                  + wsB[0] + wsB[1] + wsB[2] + wsB[3]);

    // ---- emit chunk a ----
    // wrap thread base ONCE in f64; f32 per-element accumulation
    // (max unwrapped < 1 + 8/48000 -> single fract suffices)
    float runfA = (float)(runA - floor(runA));
    float oA[VPT] = {oa0.x, oa0.y, oa0.z, oa0.w, oa1.x, oa1.y, oa1.z, oa1.w};
    float outA[VPT];
#pragma unroll
    for (int i = 0; i < VPT; ++i) {
        runfA += sa[i];
        float ph  = __builtin_amdgcn_fractf(runfA);
        float oqv = oA[i];
        float tp  = oqv * 0.66f;
        bool  is_rise  = ph < tp;
        bool  in_pulse = ph < oqv;
        float num = is_rise ? ph : (ph - tp);
        float den = is_rise ? fmaf(oqv, 0.66f, 1e-6f)    // tp + eps
                            : fmaf(oqv, 0.68f, 1e-6f);   // 2*tn + eps
        float rev = 0.5f * num * __builtin_amdgcn_rcpf(den);
        float c2  = __builtin_amdgcn_cosf(rev);
        outA[i] = is_rise ? 0.5f * (1.0f - c2) : (in_pulse ? c2 : 0.0f);
    }
    v4f* wa = (v4f*)(wav + base_a);
    { v4f v; v.x=outA[0]; v.y=outA[1]; v.z=outA[2]; v.w=outA[3]; wa[0]=v; }
    { v4f v; v.x=outA[4]; v.y=outA[5]; v.z=outA[6]; v.w=outA[7]; wa[1]=v; }

    // ---- emit chunk b ----
    float runfB = (float)(runB - floor(runB));
    float oB[VPT] = {ob0.x, ob0.y, ob0.z, ob0.w, ob1.x, ob1.y, ob1.z, ob1.w};
    float outB[VPT];
#pragma unroll
    for (int i = 0; i < VPT; ++i) {
        runfB += sb[i];
        float ph  = __builtin_amdgcn_fractf(runfB);
        float oqv = oB[i];
        float tp  = oqv * 0.66f;
        bool  is_rise  = ph < tp;
        bool  in_pulse = ph < oqv;
        float num = is_rise ? ph : (ph - tp);
        float den = is_rise ? fmaf(oqv, 0.66f, 1e-6f)
                            : fmaf(oqv, 0.68f, 1e-6f);
        float rev = 0.5f * num * __builtin_amdgcn_rcpf(den);
        float c2  = __builtin_amdgcn_cosf(rev);
        outB[i] = is_rise ? 0.5f * (1.0f - c2) : (in_pulse ? c2 : 0.0f);
    }
    v4f* wb = (v4f*)(wav + base_b);
    { v4f v; v.x=outB[0]; v.y=outB[1]; v.z=outB[2]; v.w=outB[3]; wb[0]=v; }
    { v4f v; v.x=outB[4]; v.y=outB[5]; v.z=outB[6]; v.w=outB[7]; wb[1]=v; }
}

extern "C" void kernel_launch(void* const* d_in, const int* in_sizes, int n_in,
                              void* d_out, int out_size, void* d_ws, size_t ws_size,
                              hipStream_t stream)
{
    const float* f0          = (const float*)d_in[0];
    const float* oq          = (const float*)d_in[1];
    const float* phase_state = (const float*)d_in[2];
    float* out = (float*)d_out;                 // [B*T] wav, then [B] next_state

    double* partial = (double*)d_ws;            // B*NCHUNK doubles (64 KB)

    dim3 grid1(NCHUNK, BATCH);
    k_chunk_sums<<<grid1, THREADS, 0, stream>>>(f0, partial);
    dim3 grid2(NBX, BATCH);
    k_emit<<<grid2, THREADS, 0, stream>>>(f0, oq, partial, phase_state,
                                          out, out + (size_t)BATCH * T);
}

// Round 10
// 174.189 us; speedup vs baseline: 1.1018x; 1.1018x over previous
//
#include <hip/hip_runtime.h>
#include <math.h>

// StatefulRosenberg R17: R15 (best: 174.1 us) + f32 intra-wave scan.
//
// R16 post-mortem: 2-chunk emit SPILLED (FETCH +31 MB, WRITE +39 MB =
// ~10 dwords/thread scratch round-trip; 2-chunk live state > 64-VGPR cap
// of (256,8)). Lesson: this occupancy cap fits exactly ONE chunk pipeline
// (~36 VGPR). Emit config ranking: R15 35us < R13 40.6 < R10 45 <
// R14/R16 52 < R12 147.
//
// R17's one change vs R15: intra-wave scan f64 -> f32 (cherry-picked from
// R14, whose regression was the bundled VPT=16 FETCH blowup, not this).
// The wave scan is the longest serial chain: 6 x (f64 shfl = 2 ds_bpermute
// + v_add_f64) ~500 cy -> f32 halves it. Numerics: thread sums <=1.67e-4,
// wave-inclusive <=1.07e-2, f32 scan abs err ~4e-8 << 3.9e-3 tolerance.
// Butterfly & cross-wave totals stay f64 (values ~10.9).
//
// Dead-lane ledger (measured): grid.sync/spin ~0.13us/block (R8,R12);
// per-wave barrier-free prefix (R13/R14); VPT=16 (R14: FETCH +25MB);
// 2-chunk/block at (256,8) (R16: spill); nt wav stores (R9: +30MB).
// Kept: oq pre-scan hoist (R9), chain-critical load order f0->partials->oq
// (R15), regular wav stores, nt oq loads, one f64 wrap + f32 elem accum.

constexpr int BATCH   = 16;
constexpr int T       = 1048576;
constexpr int THREADS = 256;
constexpr int VPT     = 8;                // elements per thread
constexpr int CHUNK   = THREADS * VPT;    // 2048
constexpr int NCHUNK  = T / CHUNK;        // 512

#define INV_SR (1.0f / 48000.0f)

typedef float v4f __attribute__((ext_vector_type(4)));

__device__ __forceinline__ double tree8d(const float* s) {
    return (((double)s[0] + (double)s[1]) + ((double)s[2] + (double)s[3]))
         + (((double)s[4] + (double)s[5]) + ((double)s[6] + (double)s[7]));
}

// ---------------- Pass 1: per-chunk fp64 sums (unchanged) ----------------
__global__ __launch_bounds__(THREADS, 8) void k_chunk_sums(
    const float* __restrict__ f0, double* __restrict__ partial)
{
    const int chunk = blockIdx.x;
    const int row   = blockIdx.y;
    const v4f* base = (const v4f*)(f0 + (size_t)row * T
                     + (size_t)chunk * CHUNK + (size_t)threadIdx.x * VPT);
    v4f v0 = base[0], v1 = base[1];       // regular loads: warm LLC for pass 2
    float st[VPT];
    st[0]=v0.x*INV_SR; st[1]=v0.y*INV_SR; st[2]=v0.z*INV_SR; st[3]=v0.w*INV_SR;
    st[4]=v1.x*INV_SR; st[5]=v1.y*INV_SR; st[6]=v1.z*INV_SR; st[7]=v1.w*INV_SR;
    double s = tree8d(st);
#pragma unroll
    for (int off = 32; off > 0; off >>= 1)
        s += __shfl_down(s, off, 64);
    __shared__ double ws[THREADS / 64];
    const int lane = threadIdx.x & 63, wid = threadIdx.x >> 6;
    if (lane == 0) ws[wid] = s;
    __syncthreads();
    if (threadIdx.x == 0)
        partial[row * NCHUNK + chunk] = ws[0] + ws[1] + ws[2] + ws[3];
}

// ---------------- Pass 2: prefix + intra-chunk scan + Rosenberg pulse ----
__global__ __launch_bounds__(THREADS, 8) void k_emit(
    const float* __restrict__ f0, const float* __restrict__ oq,
    const double* __restrict__ partial, const float* __restrict__ phase_state,
    float* __restrict__ wav, float* __restrict__ next_state)
{
    const int chunk = blockIdx.x;
    const int row   = blockIdx.y;
    const int lane  = threadIdx.x & 63, wid = threadIdx.x >> 6;
    const size_t base_idx = (size_t)row * T + (size_t)chunk * CHUNK
                          + (size_t)threadIdx.x * VPT;

    __shared__ double rs[THREADS / 64];   // chunk-prefix partial reduce
    __shared__ double ws[THREADS / 64];   // wave totals (f64)

    // ---- loads in CHAIN-CRITICAL order (vmcnt is ordered, oldest first):
    // (1) f0 -- first consumer (st / tsum); LLC-hot from pass 1
    const v4f* fb = (const v4f*)(f0 + base_idx);
    v4f f_0 = fb[0], f_1 = fb[1];
    // (2) chunk-prefix partials -- second consumer (butterfly); L2-hot
    double pv = 0.0;
    if ((int)threadIdx.x < chunk)       pv  = partial[row * NCHUNK + threadIdx.x];
    if ((int)threadIdx.x + 256 < chunk) pv += partial[row * NCHUNK + threadIdx.x + 256];
    const float pstate = phase_state[row];
    // (3) oq -- consumed LAST (pulse loop); HBM latency hides under
    //     butterfly + scan + barrier
    const v4f* ob = (const v4f*)(oq + base_idx);
    v4f o_0 = __builtin_nontemporal_load(ob + 0);
    v4f o_1 = __builtin_nontemporal_load(ob + 1);

    // ---- f32 steps + thread sums (f32 for scan, f64 for totals) ----
    float st[VPT];
    st[0]=f_0.x*INV_SR; st[1]=f_0.y*INV_SR; st[2]=f_0.z*INV_SR; st[3]=f_0.w*INV_SR;
    st[4]=f_1.x*INV_SR; st[5]=f_1.y*INV_SR; st[6]=f_1.z*INV_SR; st[7]=f_1.w*INV_SR;
    float ts32 = (((st[0]+st[1])+(st[2]+st[3])) + ((st[4]+st[5])+(st[6]+st[7])));
    double tsum = tree8d(st);             // f64 total feeds cross-wave path

    // ---- chunk prefix: parallel reduce of partial[row][0..chunk-1] ----
#pragma unroll
    for (int off = 32; off > 0; off >>= 1)
        pv += __shfl_down(pv, off, 64);
    if (lane == 0) rs[wid] = pv;

    // ---- intra-wave inclusive scan in f32 (serial chain halved:
    //      f32 shfl = 1 ds_bpermute vs f64's 2; err ~4e-8 << 3.9e-3 tol)
    float inc = ts32;
#pragma unroll
    for (int off = 1; off < 64; off <<= 1) {
        float n = __shfl_up(inc, off, 64);
        if (lane >= off) inc += n;
    }
    // wave total in f64 (exact per-thread f64 sums, reduced once per wave)
    double wtot = tsum;
#pragma unroll
    for (int off = 32; off > 0; off >>= 1)
        wtot += __shfl_down(wtot, off, 64);
    if (lane == 0) ws[wid] = wtot;
    __syncthreads();

    const double chunkpref = rs[0] + rs[1] + rs[2] + rs[3];
    double run = (double)pstate + chunkpref + (double)(inc - ts32);
#pragma unroll
    for (int w = 0; w < THREADS / 64; ++w)
        if (w < wid) run += ws[w];

    // next_state: unwrapped final phase, written by the last chunk's thread 0
    if (chunk == NCHUNK - 1 && threadIdx.x == 0)
        next_state[row] = (float)((double)pstate + chunkpref
                                  + ws[0] + ws[1] + ws[2] + ws[3]);

    // wrap the thread base ONCE in f64; per-element accumulation is f32.
    // max unwrapped value < 1 + 8*(1/48000) -> single fract suffices.
    float runf = (float)(run - floor(run));

    float o[VPT];
    o[0]=o_0.x; o[1]=o_0.y; o[2]=o_0.z; o[3]=o_0.w;
    o[4]=o_1.x; o[5]=o_1.y; o[6]=o_1.z; o[7]=o_1.w;

    // ---- accumulate + pulse; one v_cos per element, arg in revolutions ----
    float outv[VPT];
#pragma unroll
    for (int i = 0; i < VPT; ++i) {
        runf += st[i];
        float ph  = __builtin_amdgcn_fractf(runf);   // wrapped phase in [0,1)
        float oqv = o[i];
        float tp  = oqv * 0.66f;
        bool  is_rise  = ph < tp;
        bool  in_pulse = ph < oqv;
        float num = is_rise ? ph : (ph - tp);
        float den = is_rise ? fmaf(oqv, 0.66f, 1e-6f)    // tp + eps
                            : fmaf(oqv, 0.68f, 1e-6f);   // 2*tn + eps
        // cos(pi * num/den) == v_cos(0.5 * num/den revolutions)
        float rev = 0.5f * num * __builtin_amdgcn_rcpf(den);
        float c2  = __builtin_amdgcn_cosf(rev);
        outv[i] = is_rise ? 0.5f * (1.0f - c2) : (in_pulse ? c2 : 0.0f);
    }

    v4f* wb = (v4f*)(wav + base_idx);
#pragma unroll
    for (int j = 0; j < VPT / 4; ++j) {
        v4f vv;
        vv.x = outv[4 * j + 0]; vv.y = outv[4 * j + 1];
        vv.z = outv[4 * j + 2]; vv.w = outv[4 * j + 3];
        wb[j] = vv;   // regular store: L2 merges partial lines (R9 lesson)
    }
}

extern "C" void kernel_launch(void* const* d_in, const int* in_sizes, int n_in,
                              void* d_out, int out_size, void* d_ws, size_t ws_size,
                              hipStream_t stream)
{
    const float* f0          = (const float*)d_in[0];
    const float* oq          = (const float*)d_in[1];
    const float* phase_state = (const float*)d_in[2];
    float* out = (float*)d_out;                 // [B*T] wav, then [B] next_state

    double* partial = (double*)d_ws;            // B*NCHUNK doubles (64 KB)

    dim3 grid(NCHUNK, BATCH);
    k_chunk_sums<<<grid, THREADS, 0, stream>>>(f0, partial);
    k_emit<<<grid, THREADS, 0, stream>>>(f0, oq, partial, phase_state,
                                         out, out + (size_t)BATCH * T);
}